// Round 3
// baseline (415.906 us; speedup 1.0000x reference)
//
#include <hip/hip_runtime.h>

// B=16, S=4096, V=1024, fp32.
// Restructured: never materialize K/V.
//   q[b,o]   = pool[b]·Wq[o,:] + bq[o]
//   qks[b,v] = (1/64) * sum_o q[b,o] Wk[o,v];  c[b] = (1/64) q[b]·bk
//   a[b,s]   = qks[b]·bert[b,s] + c[b]
//   u[b,v]   = sum_s a[b,s] bert[b,s,v];  A[b] = sum_s a[b,s]
//   out[b,d] = Wv[d,:]·u[b] + bv[d]*A[b]
//
// R2 changes (model: ~330us of timed harness poison-fill + ~43us bert floor
// + ~25us small kernels; only the last is a lever):
//   - k_qk vectorized: 16 vf4 Wk loads per wave (was 64 scalar loads/thread),
//     4-wave dd-split, atomic combine (atomics measured free in R0/R1).
//   - k_red deleted; k_main reverts to the proven R0 atomic epilogue.
//
// Workspace layout (floats):
//   q   [0      : 16384)
//   qks [16384  : 32768)   zeroed by k_xw<0>   (contiguous with c)
//   c   [32768  : 32784)   zeroed by k_xw<0>
//   u   [32784  : 49168)   zeroed by k_qk      (contiguous with A)
//   A   [49168  : 49184)   zeroed by k_qk

#define BB 16
#define SS 4096
#define VV 1024
#define V4 256   // VV/4

// native clang vector type — required by __builtin_nontemporal_load
typedef float vf4 __attribute__((ext_vector_type(4)));

__device__ __forceinline__ float dot4(const vf4& a, const vf4& b) {
    return a.x*b.x + a.y*b.y + a.z*b.z + a.w*b.w;
}

__device__ __forceinline__ void axpy4(float a, const vf4& x, vf4& y) {
    y.x = fmaf(a, x.x, y.x); y.y = fmaf(a, x.y, y.y);
    y.z = fmaf(a, x.z, y.z); y.w = fmaf(a, x.w, y.w);
}

__device__ __forceinline__ float wave_allreduce(float v) {
#pragma unroll
    for (int off = 32; off > 0; off >>= 1)
        v += __shfl_xor(v, off, 64);
    return v;
}

// Y[b,o] = X[b,:]·W[o,:] + bias term.  X (16x1024 = 64 KB) staged in LDS once
// per block; each weight row read exactly once chip-wide (4 MB total).
// Grid 256 blocks x 256 thr; wave w handles o = blockIdx*4 + w.
// OUT_MODE=0: Y = X@W^T + bias[o]; also zeroes zbuf (qks+c, 16400 floats).
// OUT_MODE=1: Y = X@W^T + bias[o]*scale[b] (output projection, scale = A)
template <int OUT_MODE>
__global__ __launch_bounds__(256) void k_xw(const float* __restrict__ X,
                                            const float* __restrict__ W,
                                            const float* __restrict__ bias,
                                            const float* __restrict__ scale,
                                            float* __restrict__ Y,
                                            float* __restrict__ zbuf) {
    if (OUT_MODE == 0) {
        // 256 blocks x 65 floats covers 16400
        int zi = blockIdx.x * 65 + threadIdx.x;
        if (threadIdx.x < 65 && zi < 16400) zbuf[zi] = 0.f;
    }
    __shared__ vf4 Xls[BB * V4];   // 64 KB
    const vf4* X4 = (const vf4*)X;
    for (int i = threadIdx.x; i < BB * V4; i += 256) Xls[i] = X4[i];
    __syncthreads();

    int w = threadIdx.x >> 6, lane = threadIdx.x & 63;
    int o = blockIdx.x * 4 + w;
    const vf4* w4 = (const vf4*)W + (size_t)o * V4;
    vf4 wv0 = w4[lane], wv1 = w4[64 + lane], wv2 = w4[128 + lane], wv3 = w4[192 + lane];

    float acc[BB];
#pragma unroll
    for (int b = 0; b < BB; ++b) {
        const vf4* xb = &Xls[b * V4];
        acc[b] = dot4(wv0, xb[lane]) + dot4(wv1, xb[64 + lane])
               + dot4(wv2, xb[128 + lane]) + dot4(wv3, xb[192 + lane]);
    }
#pragma unroll
    for (int b = 0; b < BB; ++b) acc[b] = wave_allreduce(acc[b]);
    if (lane < BB) {
        int b = lane;
        float bias_t = OUT_MODE ? bias[o] * scale[b] : bias[o];
        Y[b * VV + o] = acc[b] + bias_t;
    }
}

// qks[b,v] = (1/64) * sum_o q[b,o] Wk[o,v]  (atomic combine over o-chunks);
// vc==0 blocks also produce c[b] = (1/64) q[b]·bk partials.
// Also zeroes zbuf (u+A, 16400 floats) for k_main's atomic epilogue.
// Grid 64 blocks (dc 0..15 x vc 0..3) x 256 thr.
// Wave w covers dd = w*16..w*16+15 with vf4 loads (coalesced 1KB/wave-inst,
// 16 independent loads -> deep vmem pipeline; was 64 serial scalar loads).
__global__ __launch_bounds__(256) void k_qk(const float* __restrict__ q,
                                            const float* __restrict__ Wk,
                                            const float* __restrict__ bk,
                                            float* __restrict__ qks,
                                            float* __restrict__ c,
                                            float* __restrict__ zbuf) {
    {
        int gtid = blockIdx.x * 256 + threadIdx.x;   // 64*256 = 16384 threads
        for (int i = gtid; i < 16400; i += 16384) zbuf[i] = 0.f;
    }
    __shared__ float qs[BB][64];
    int vc = blockIdx.x & 3, dc = blockIdx.x >> 2;
    int dlo = dc * 64;
    for (int i = threadIdx.x; i < BB * 64; i += 256) {
        int b = i >> 6, dd = i & 63;
        qs[b][dd] = q[b * VV + dlo + dd];
    }
    __syncthreads();

    int w = threadIdx.x >> 6, lane = threadIdx.x & 63;
    const vf4* Wk4 = (const vf4*)Wk;       // row stride V4 vf4
    int vbase = vc * 64 + lane;            // vf4 column index within row
    vf4 acc[BB];
#pragma unroll
    for (int b = 0; b < BB; ++b) acc[b] = vf4{0, 0, 0, 0};
#pragma unroll
    for (int j = 0; j < 16; ++j) {
        int dd = w * 16 + j;
        vf4 wk = Wk4[(size_t)(dlo + dd) * V4 + vbase];
#pragma unroll
        for (int b = 0; b < BB; ++b) axpy4(qs[b][dd], wk, acc[b]);
    }
#pragma unroll
    for (int b = 0; b < BB; ++b) {
        float* dst = qks + b * VV + vbase * 4;
        atomicAdd(dst + 0, acc[b].x * 0.015625f);
        atomicAdd(dst + 1, acc[b].y * 0.015625f);
        atomicAdd(dst + 2, acc[b].z * 0.015625f);
        atomicAdd(dst + 3, acc[b].w * 0.015625f);
    }

    if (vc == 0 && threadIdx.x < 64) {
        int lane2 = threadIdx.x;
        float bkv = bk[dlo + lane2];
#pragma unroll
        for (int b = 0; b < BB; ++b) {
            float r = wave_allreduce(qs[b][lane2] * bkv);
            if (lane2 == 0) atomicAdd(&c[b], r * 0.015625f);
        }
    }
}

// Fused attention pass: single read of bert (256 MB), non-temporal (no reuse).
// Each wave owns 16 consecutive s rows in 4 batches of 4 rows (deep vmcnt
// pipeline + interleaved butterfly chains).  4-wave LDS combine, one atomic
// per elem per block (atomics measured free in R0/R1 A/B).
// 1024 blocks x 256 thr.
__global__ __launch_bounds__(256) void k_main(const float* __restrict__ bert,
                                              const float* __restrict__ qks,
                                              const float* __restrict__ c,
                                              float* __restrict__ u,
                                              float* __restrict__ A) {
    int w = threadIdx.x >> 6, lane = threadIdx.x & 63;
    int b = blockIdx.x >> 6, sc = blockIdx.x & 63;   // 64 blocks per batch
    int s0 = sc * 64 + w * 16;                       // 16 s per wave
    const vf4* qk4 = (const vf4*)qks + b * V4;
    vf4 k0 = qk4[lane], k1 = qk4[64 + lane], k2 = qk4[128 + lane], k3 = qk4[192 + lane];
    float cb = c[b];
    vf4 u0 = {0,0,0,0}, u1 = {0,0,0,0}, u2 = {0,0,0,0}, u3 = {0,0,0,0};
    float asum = 0.f;
    const vf4* base = (const vf4*)bert + ((size_t)b * SS + s0) * V4;

#pragma unroll
    for (int t = 0; t < 4; ++t) {
        // --- load 4 rows (16 vf4 loads in flight) ---
        vf4 x[4][4];
#pragma unroll
        for (int s = 0; s < 4; ++s) {
            const vf4* row = base + (size_t)(t * 4 + s) * V4;
#pragma unroll
            for (int j = 0; j < 4; ++j)
                x[s][j] = __builtin_nontemporal_load(row + j * 64 + lane);
        }
        // --- 4 partial dots ---
        float p[4];
#pragma unroll
        for (int s = 0; s < 4; ++s)
            p[s] = dot4(k0, x[s][0]) + dot4(k1, x[s][1])
                 + dot4(k2, x[s][2]) + dot4(k3, x[s][3]);
        // --- 4 independent butterfly chains, interleaved ---
#pragma unroll
        for (int off = 32; off > 0; off >>= 1) {
#pragma unroll
            for (int s = 0; s < 4; ++s)
                p[s] += __shfl_xor(p[s], off, 64);
        }
        // --- scale-and-accumulate ---
#pragma unroll
        for (int s = 0; s < 4; ++s) {
            float a = p[s] + cb;
            axpy4(a, x[s][0], u0); axpy4(a, x[s][1], u1);
            axpy4(a, x[s][2], u2); axpy4(a, x[s][3], u3);
            asum += a;
        }
    }

    // combine 4 waves in LDS, then one atomic per element per block
    __shared__ vf4 uls[4][256];
    __shared__ float as_[4];
    uls[w][lane]       = u0;
    uls[w][64 + lane]  = u1;
    uls[w][128 + lane] = u2;
    uls[w][192 + lane] = u3;
    if (lane == 0) as_[w] = asum;
    __syncthreads();
    int t = threadIdx.x;
    vf4 a0 = uls[0][t], a1 = uls[1][t], a2 = uls[2][t], a3 = uls[3][t];
    float* up = u + (size_t)b * VV + 4 * t;
    atomicAdd(up + 0, a0.x + a1.x + a2.x + a3.x);
    atomicAdd(up + 1, a0.y + a1.y + a2.y + a3.y);
    atomicAdd(up + 2, a0.z + a1.z + a2.z + a3.z);
    atomicAdd(up + 3, a0.w + a1.w + a2.w + a3.w);
    if (t == 0) atomicAdd(&A[b], as_[0] + as_[1] + as_[2] + as_[3]);
}

extern "C" void kernel_launch(void* const* d_in, const int* in_sizes, int n_in,
                              void* d_out, int out_size, void* d_ws, size_t ws_size,
                              hipStream_t stream) {
    const float* pool = (const float*)d_in[0];
    const float* bert = (const float*)d_in[1];
    const float* Wq   = (const float*)d_in[2];
    const float* bq   = (const float*)d_in[3];
    const float* Wk   = (const float*)d_in[4];
    const float* bk   = (const float*)d_in[5];
    const float* Wv   = (const float*)d_in[6];
    const float* bv   = (const float*)d_in[7];
    float* out = (float*)d_out;

    float* ws  = (float*)d_ws;
    float* q   = ws;            // 16384 floats
    float* qks = ws + 16384;    // 16384 floats (zeroed by k_xw<0>)
    float* c   = ws + 32768;    // 16 floats    (zeroed by k_xw<0>)
    float* u   = ws + 32784;    // 16384 floats (zeroed by k_qk)
    float* A   = ws + 49168;    // 16 floats    (zeroed by k_qk)

    k_xw<0><<<256,  256, 0, stream>>>(pool, Wq, bq, nullptr, q, qks);
    k_qk   <<<64,   256, 0, stream>>>(q, Wk, bk, qks, c, u);
    k_main <<<1024, 256, 0, stream>>>(bert, qks, c, u, A);
    k_xw<1><<<256,  256, 0, stream>>>(u, Wv, bv, A, out, nullptr);
}

// Round 4
// 397.745 us; speedup vs baseline: 1.0457x; 1.0457x over previous
//
#include <hip/hip_runtime.h>

// B=16, S=4096, V=1024, fp32.
// Restructured: never materialize K/V.
//   q[b,o]   = pool[b]·Wq[o,:] + bq[o]
//   qks[b,v] = (1/64) * sum_o q[b,o] Wk[o,v];  c[b] = (1/64) q[b]·bk
//   a[b,s]   = qks[b]·bert[b,s] + c[b]
//   u[b,v]   = sum_s a[b,s] bert[b,s,v];  A[b] = sum_s a[b,s]
//   out[b,d] = Wv[d,:]·u[b] + bv[d]*A[b]
//
// R3: REVERT to the best-measured configuration (394.2 us).  Session findings:
//   - batch-4 reduce restructure of k_main: neutral (R0)
//   - atomic epilogue vs partial-stores+k_red:  neutral (R1) -> atomics free under k_main
//   - k_qk 4x atomic inflation: -16 us REGRESSION (R2) -> reverted
// Accounting model: timed window = ~320 us harness poison-fill (2x 1GiB @6.7TB/s)
// + ~43 us bert floor (268 MB, single mandatory pass) + ~30 us small kernels.
//
// Workspace layout (floats):
//   q   [0      : 16384)
//   qks [16384  : 32768)   zeroed by k_xw<0>   (contiguous with c)
//   c   [32768  : 32784)   zeroed by k_xw<0>
//   u   [32784  : 49168)   zeroed by k_qk      (contiguous with A)
//   A   [49168  : 49184)   zeroed by k_qk

#define BB 16
#define SS 4096
#define VV 1024
#define V4 256   // VV/4

// native clang vector type — required by __builtin_nontemporal_load
typedef float vf4 __attribute__((ext_vector_type(4)));

__device__ __forceinline__ float dot4(const vf4& a, const vf4& b) {
    return a.x*b.x + a.y*b.y + a.z*b.z + a.w*b.w;
}

__device__ __forceinline__ void axpy4(float a, const vf4& x, vf4& y) {
    y.x = fmaf(a, x.x, y.x); y.y = fmaf(a, x.y, y.y);
    y.z = fmaf(a, x.z, y.z); y.w = fmaf(a, x.w, y.w);
}

__device__ __forceinline__ float wave_allreduce(float v) {
#pragma unroll
    for (int off = 32; off > 0; off >>= 1)
        v += __shfl_xor(v, off, 64);
    return v;
}

// Y[b,o] = X[b,:]·W[o,:] + bias term.  X (16x1024 = 64 KB) staged in LDS once
// per block; each weight row read exactly once chip-wide (4 MB total).
// Grid 256 blocks x 256 thr; wave w handles o = blockIdx*4 + w.
// OUT_MODE=0: Y = X@W^T + bias[o]; also zeroes zbuf (qks+c, 16400 floats).
// OUT_MODE=1: Y = X@W^T + bias[o]*scale[b] (output projection, scale = A)
template <int OUT_MODE>
__global__ __launch_bounds__(256) void k_xw(const float* __restrict__ X,
                                            const float* __restrict__ W,
                                            const float* __restrict__ bias,
                                            const float* __restrict__ scale,
                                            float* __restrict__ Y,
                                            float* __restrict__ zbuf) {
    if (OUT_MODE == 0) {
        // 256 blocks x 65 floats covers 16400
        int zi = blockIdx.x * 65 + threadIdx.x;
        if (threadIdx.x < 65 && zi < 16400) zbuf[zi] = 0.f;
    }
    __shared__ vf4 Xls[BB * V4];   // 64 KB
    const vf4* X4 = (const vf4*)X;
    for (int i = threadIdx.x; i < BB * V4; i += 256) Xls[i] = X4[i];
    __syncthreads();

    int w = threadIdx.x >> 6, lane = threadIdx.x & 63;
    int o = blockIdx.x * 4 + w;
    const vf4* w4 = (const vf4*)W + (size_t)o * V4;
    vf4 wv0 = w4[lane], wv1 = w4[64 + lane], wv2 = w4[128 + lane], wv3 = w4[192 + lane];

    float acc[BB];
#pragma unroll
    for (int b = 0; b < BB; ++b) {
        const vf4* xb = &Xls[b * V4];
        acc[b] = dot4(wv0, xb[lane]) + dot4(wv1, xb[64 + lane])
               + dot4(wv2, xb[128 + lane]) + dot4(wv3, xb[192 + lane]);
    }
#pragma unroll
    for (int b = 0; b < BB; ++b) acc[b] = wave_allreduce(acc[b]);
    if (lane < BB) {
        int b = lane;
        float bias_t = OUT_MODE ? bias[o] * scale[b] : bias[o];
        Y[b * VV + o] = acc[b] + bias_t;
    }
}

// qks[b,v] = (1/64) * sum_o q[b,o] Wk[o,v]  (atomic combine over o-chunks);
// vc==0 blocks also produce c[b] = (1/64) q[b]·bk partials.
// Also zeroes zbuf (u+A, 16400 floats) for k_main.
__global__ __launch_bounds__(256) void k_qk(const float* __restrict__ q,
                                            const float* __restrict__ Wk,
                                            const float* __restrict__ bk,
                                            float* __restrict__ qks,
                                            float* __restrict__ c,
                                            float* __restrict__ zbuf) {
    {
        int gtid = blockIdx.x * 256 + threadIdx.x;   // 64*256 = 16384 threads
        for (int i = gtid; i < 16400; i += 16384) zbuf[i] = 0.f;
    }
    __shared__ float qs[BB][64];
    int vc = blockIdx.x & 3, dc = blockIdx.x >> 2;
    int dlo = dc * 64;
    for (int i = threadIdx.x; i < BB * 64; i += 256) {
        int b = i >> 6, dd = i & 63;
        qs[b][dd] = q[b * VV + dlo + dd];
    }
    __syncthreads();
    int v = (vc << 8) + threadIdx.x;
    float acc[BB];
#pragma unroll
    for (int b = 0; b < BB; ++b) acc[b] = 0.f;
    for (int dd = 0; dd < 64; ++dd) {
        float wk = Wk[(size_t)(dlo + dd) * VV + v];
#pragma unroll
        for (int b = 0; b < BB; ++b) acc[b] = fmaf(qs[b][dd], wk, acc[b]);
    }
#pragma unroll
    for (int b = 0; b < BB; ++b)
        atomicAdd(&qks[b * VV + v], acc[b] * 0.015625f);

    if (vc == 0 && threadIdx.x < 64) {
        int lane = threadIdx.x;
        float bkv = bk[dlo + lane];
#pragma unroll
        for (int b = 0; b < BB; ++b) {
            float r = wave_allreduce(qs[b][lane] * bkv);
            if (lane == 0) atomicAdd(&c[b], r * 0.015625f);
        }
    }
}

// Fused attention pass: single read of bert (256 MB), non-temporal (no reuse).
// Each wave owns 16 consecutive s rows: a = qks·row + c (butterfly reduce),
// u += a*row in registers. 4-wave LDS combine, one atomic per elem per block.
// 1024 blocks x 256 thr.
__global__ __launch_bounds__(256) void k_main(const float* __restrict__ bert,
                                              const float* __restrict__ qks,
                                              const float* __restrict__ c,
                                              float* __restrict__ u,
                                              float* __restrict__ A) {
    int w = threadIdx.x >> 6, lane = threadIdx.x & 63;
    int b = blockIdx.x >> 6, sc = blockIdx.x & 63;   // 64 blocks per batch
    int s0 = sc * 64 + w * 16;                       // 16 s per wave
    const vf4* qk4 = (const vf4*)qks + b * V4;
    vf4 k0 = qk4[lane], k1 = qk4[64 + lane], k2 = qk4[128 + lane], k3 = qk4[192 + lane];
    float cb = c[b];
    vf4 u0 = {0,0,0,0}, u1 = {0,0,0,0}, u2 = {0,0,0,0}, u3 = {0,0,0,0};
    float asum = 0.f;
    const vf4* base = (const vf4*)bert + ((size_t)b * SS + s0) * V4;
#pragma unroll 4
    for (int s = 0; s < 16; ++s) {
        const vf4* row = base + (size_t)s * V4;
        vf4 x0 = __builtin_nontemporal_load(row + lane);
        vf4 x1 = __builtin_nontemporal_load(row + 64 + lane);
        vf4 x2 = __builtin_nontemporal_load(row + 128 + lane);
        vf4 x3 = __builtin_nontemporal_load(row + 192 + lane);
        float p = dot4(k0, x0) + dot4(k1, x1) + dot4(k2, x2) + dot4(k3, x3);
        p = wave_allreduce(p);               // all lanes hold full sum
        float a = p + cb;
        axpy4(a, x0, u0); axpy4(a, x1, u1); axpy4(a, x2, u2); axpy4(a, x3, u3);
        asum += a;
    }
    // combine 4 waves in LDS, then one atomic per element per block
    __shared__ vf4 uls[4][256];
    __shared__ float as_[4];
    uls[w][lane]       = u0;
    uls[w][64 + lane]  = u1;
    uls[w][128 + lane] = u2;
    uls[w][192 + lane] = u3;
    if (lane == 0) as_[w] = asum;
    __syncthreads();
    int t = threadIdx.x;
    vf4 a0 = uls[0][t], a1 = uls[1][t], a2 = uls[2][t], a3 = uls[3][t];
    float* up = u + (size_t)b * VV + 4 * t;
    atomicAdd(up + 0, a0.x + a1.x + a2.x + a3.x);
    atomicAdd(up + 1, a0.y + a1.y + a2.y + a3.y);
    atomicAdd(up + 2, a0.z + a1.z + a2.z + a3.z);
    atomicAdd(up + 3, a0.w + a1.w + a2.w + a3.w);
    if (t == 0) atomicAdd(&A[b], as_[0] + as_[1] + as_[2] + as_[3]);
}

extern "C" void kernel_launch(void* const* d_in, const int* in_sizes, int n_in,
                              void* d_out, int out_size, void* d_ws, size_t ws_size,
                              hipStream_t stream) {
    const float* pool = (const float*)d_in[0];
    const float* bert = (const float*)d_in[1];
    const float* Wq   = (const float*)d_in[2];
    const float* bq   = (const float*)d_in[3];
    const float* Wk   = (const float*)d_in[4];
    const float* bk   = (const float*)d_in[5];
    const float* Wv   = (const float*)d_in[6];
    const float* bv   = (const float*)d_in[7];
    float* out = (float*)d_out;

    float* ws  = (float*)d_ws;
    float* q   = ws;            // 16384 floats
    float* qks = ws + 16384;    // 16384 floats (zeroed by k_xw<0>)
    float* c   = ws + 32768;    // 16 floats    (zeroed by k_xw<0>)
    float* u   = ws + 32784;    // 16384 floats (zeroed by k_qk)
    float* A   = ws + 49168;    // 16 floats    (zeroed by k_qk)

    k_xw<0><<<256,  256, 0, stream>>>(pool, Wq, bq, nullptr, q, qks);
    k_qk   <<<64,   256, 0, stream>>>(q, Wk, bk, qks, c, u);
    k_main <<<1024, 256, 0, stream>>>(bert, qks, c, u, A);
    k_xw<1><<<256,  256, 0, stream>>>(u, Wv, bv, A, out, nullptr);
}